// Round 4
// baseline (843.160 us; speedup 1.0000x reference)
//
#include <hip/hip_runtime.h>

#define D 64
#define SCAN_CHUNK 1024

// ---------------- rel kernel: R = rel_emb @ Wf^T ; rel_out = rel_emb @ Wrel^T
__global__ __launch_bounds__(256) void rel_kernel(
    const float* __restrict__ rel_emb,
    const float* __restrict__ W_f,
    const float* __restrict__ W_rel,
    float* __restrict__ R,
    float* __restrict__ rel_out,
    int n_rel) {
  __shared__ float WtF[D][D];
  __shared__ float WtR[D][D];
  int tid = threadIdx.x;
  for (int idx = tid; idx < D * D; idx += 256) {
    int j = idx >> 6, k = idx & 63;
    WtF[k][j] = W_f[idx];
    WtR[k][j] = W_rel[idx];
  }
  __syncthreads();
  int lane = tid & 63, wave = tid >> 6;
  for (int r = blockIdx.x * 4 + wave; r < n_rel; r += gridDim.x * 4) {
    const float4* a = (const float4*)(rel_emb + (size_t)r * D);
    float accR = 0.f, accO = 0.f;
#pragma unroll
    for (int k4 = 0; k4 < 16; ++k4) {
      float4 av = a[k4];
      int k = k4 * 4;
      accR += av.x * WtF[k][lane] + av.y * WtF[k + 1][lane] +
              av.z * WtF[k + 2][lane] + av.w * WtF[k + 3][lane];
      accO += av.x * WtR[k][lane] + av.y * WtR[k + 1][lane] +
              av.z * WtR[k + 2][lane] + av.w * WtR[k + 3][lane];
    }
    R[(size_t)r * D + lane] = accR;
    rel_out[(size_t)r * D + lane] = accO;
  }
}

// ---------------- fused node GEMV: out = nf@Ws^T + bias ; X = nf@Wf^T
// Lane j holds rows j of W_self and W_forward in VGPRs, PINNED via opaque asm
// so the compiler cannot rematerialize the loads inside the row loop
// (R3 failure mode: VGPR_Count=32 -> W re-loaded per row -> 772 MB FETCH).
__global__ __launch_bounds__(256, 3) void node_fused(
    const float* __restrict__ nf,
    const float* __restrict__ W_self,
    const float* __restrict__ W_f,
    const float* __restrict__ bias,
    float* __restrict__ out,
    float* __restrict__ X,
    int n_nodes) {
  int lane = threadIdx.x & 63;

  float4 ws[16], wf[16];
  const float4* Wsv = (const float4*)(W_self + lane * D);
  const float4* Wfv = (const float4*)(W_f + lane * D);
#pragma unroll
  for (int k = 0; k < 16; ++k) {
    ws[k] = Wsv[k];
    wf[k] = Wfv[k];
  }
#pragma unroll
  for (int k = 0; k < 16; ++k) {
    asm volatile("" : "+v"(ws[k].x), "+v"(ws[k].y), "+v"(ws[k].z), "+v"(ws[k].w));
    asm volatile("" : "+v"(wf[k].x), "+v"(wf[k].y), "+v"(wf[k].z), "+v"(wf[k].w));
  }
  float b = bias[lane];

  int wave_id = (int)((blockIdx.x * blockDim.x + threadIdx.x) >> 6);
  int n_waves = (int)((gridDim.x * blockDim.x) >> 6);

  for (int row = wave_id; row < n_nodes; row += n_waves) {
    const float4* a = (const float4*)(nf + (size_t)row * D);
    float s0 = 0.f, s1 = 0.f, f0 = 0.f, f1 = 0.f;  // dual acc: break dep chain
#pragma unroll
    for (int k = 0; k < 16; k += 2) {
      float4 a0 = a[k];      // wave-uniform address -> broadcast transaction
      float4 a1 = a[k + 1];
      s0 += a0.x * ws[k].x + a0.y * ws[k].y + a0.z * ws[k].z + a0.w * ws[k].w;
      f0 += a0.x * wf[k].x + a0.y * wf[k].y + a0.z * wf[k].z + a0.w * wf[k].w;
      s1 += a1.x * ws[k+1].x + a1.y * ws[k+1].y + a1.z * ws[k+1].z + a1.w * ws[k+1].w;
      f1 += a1.x * wf[k+1].x + a1.y * wf[k+1].y + a1.z * wf[k+1].z + a1.w * wf[k+1].w;
    }
    out[(size_t)row * D + lane] = s0 + s1 + b;
    X[(size_t)row * D + lane] = f0 + f1;
  }
}

// ---------------- CSR build ----------------
__global__ __launch_bounds__(256) void k_zero(int* __restrict__ p, int n) {
  int i = blockIdx.x * blockDim.x + threadIdx.x;
  int stride = gridDim.x * blockDim.x;
  for (; i < n; i += stride) p[i] = 0;
}

__global__ __launch_bounds__(256) void k_hist(
    const int* __restrict__ dst, const int* __restrict__ dir,
    int* __restrict__ cnt, int n_edges) {
  int i = blockIdx.x * blockDim.x + threadIdx.x;
  int stride = gridDim.x * blockDim.x;
  for (; i < n_edges; i += stride)
    if (dir[i] == 0) atomicAdd(&cnt[dst[i]], 1);
}

__global__ __launch_bounds__(256) void k_sums(
    const int* __restrict__ cnt, int* __restrict__ sums, int n) {
  __shared__ int ws_[4];
  int b = blockIdx.x, t = threadIdx.x;
  int lane = t & 63, wave = t >> 6;
  int s = 0;
  for (int j = 0; j < 4; ++j) {
    int i = b * SCAN_CHUNK + t * 4 + j;
    if (i < n) s += cnt[i];
  }
  for (int off = 32; off; off >>= 1) s += __shfl_down(s, off);
  if (lane == 0) ws_[wave] = s;
  __syncthreads();
  if (t == 0) sums[b] = ws_[0] + ws_[1] + ws_[2] + ws_[3];
}

__global__ __launch_bounds__(1024) void k_scan_sums(int* __restrict__ sums, int nblk) {
  __shared__ int l[1024];
  int t = threadIdx.x;
  l[t] = (t < nblk) ? sums[t] : 0;
  __syncthreads();
  for (int d = 1; d < 1024; d <<= 1) {
    int v = (t >= d) ? l[t - d] : 0;
    __syncthreads();
    l[t] += v;
    __syncthreads();
  }
  if (t < nblk) sums[t] = (t == 0) ? 0 : l[t - 1];
}

__global__ __launch_bounds__(256) void k_scan_chunks(
    int* __restrict__ cnt, const int* __restrict__ sums, int n) {
  __shared__ int wsum[4];
  int b = blockIdx.x, t = threadIdx.x;
  int lane = t & 63, wave = t >> 6;
  int i0 = b * SCAN_CHUNK + t * 4;
  int c0 = (i0 + 0 < n) ? cnt[i0 + 0] : 0;
  int c1 = (i0 + 1 < n) ? cnt[i0 + 1] : 0;
  int c2 = (i0 + 2 < n) ? cnt[i0 + 2] : 0;
  int c3 = (i0 + 3 < n) ? cnt[i0 + 3] : 0;
  int s = c0 + c1 + c2 + c3;
  int inc = s;
  for (int d = 1; d < 64; d <<= 1) {
    int v = __shfl_up(inc, d);
    if (lane >= d) inc += v;
  }
  if (lane == 63) wsum[wave] = inc;
  __syncthreads();
  int wbase = 0;
  if (wave > 0) wbase += wsum[0];
  if (wave > 1) wbase += wsum[1];
  if (wave > 2) wbase += wsum[2];
  int ex = sums[b] + wbase + inc - s;
  if (i0 + 0 < n) cnt[i0 + 0] = ex;
  if (i0 + 1 < n) cnt[i0 + 1] = ex + c0;
  if (i0 + 2 < n) cnt[i0 + 2] = ex + c0 + c1;
  if (i0 + 3 < n) cnt[i0 + 3] = ex + c0 + c1 + c2;
}

__global__ __launch_bounds__(256) void k_scatter(
    const int* __restrict__ dst, const int* __restrict__ dir,
    int* __restrict__ cursor, int* __restrict__ perm, int n_edges) {
  int i = blockIdx.x * blockDim.x + threadIdx.x;
  int stride = gridDim.x * blockDim.x;
  for (; i < n_edges; i += stride)
    if (dir[i] == 0) {
      int pos = atomicAdd(&cursor[dst[i]], 1);
      perm[pos] = i;
    }
}

// ---------------- gather: out[n] += sum_{e in bucket(n)} X[src[e]] - R[et[e]]
__global__ __launch_bounds__(256) void k_gather(
    const int* __restrict__ cursor, const int* __restrict__ perm,
    const int* __restrict__ src, const int* __restrict__ etype,
    const float* __restrict__ X, const float* __restrict__ R,
    float* __restrict__ out, int n_nodes) {
  int lane = threadIdx.x & 63;
  int wave_id = (int)((blockIdx.x * blockDim.x + threadIdx.x) >> 6);
  int n_waves = (int)((gridDim.x * blockDim.x) >> 6);
  for (int node = wave_id; node < n_nodes; node += n_waves) {
    int end = cursor[node];
    int beg = (node == 0) ? 0 : cursor[node - 1];
    if (end <= beg) continue;
    float acc = 0.f;
    int k = beg;
    for (; k + 1 < end; k += 2) {
      int e0 = perm[k], e1 = perm[k + 1];
      int s0 = src[e0], t0 = etype[e0];
      int s1 = src[e1], t1 = etype[e1];
      float a0 = X[(size_t)s0 * D + lane] - R[(size_t)t0 * D + lane];
      float a1 = X[(size_t)s1 * D + lane] - R[(size_t)t1 * D + lane];
      acc += a0 + a1;
    }
    if (k < end) {
      int e0 = perm[k];
      acc += X[(size_t)src[e0] * D + lane] - R[(size_t)etype[e0] * D + lane];
    }
    out[(size_t)node * D + lane] += acc;
  }
}

// ---------------- fallback edge kernel (atomic) ----------------
__global__ __launch_bounds__(256) void edge_atomic(
    const int* __restrict__ src, const int* __restrict__ dst,
    const int* __restrict__ et, const int* __restrict__ dir,
    const float* __restrict__ X, const float* __restrict__ R,
    float* __restrict__ out, int n_edges) {
  int lane = threadIdx.x & 63;
  long long wave_id = ((long long)blockIdx.x * blockDim.x + threadIdx.x) >> 6;
  long long n_waves = ((long long)gridDim.x * blockDim.x) >> 6;
  for (long long base = wave_id * 64; base < n_edges; base += n_waves * 64) {
    int e = (int)base + lane;
    int s_l = 0, d_l = 0, t_l = 0, dir_l = 1;
    if (e < n_edges) {
      s_l = src[e]; d_l = dst[e]; t_l = et[e]; dir_l = dir[e];
    }
    int cnt = min(64, n_edges - (int)base);
    for (int i = 0; i < cnt; ++i) {
      int dir_i = __shfl(dir_l, i);
      if (dir_i != 0) continue;
      int s_i = __shfl(s_l, i);
      int t_i = __shfl(t_l, i);
      int d_i = __shfl(d_l, i);
      float val = X[(size_t)s_i * D + lane] - R[(size_t)t_i * D + lane];
      atomicAdd(&out[(size_t)d_i * D + lane], val);
    }
  }
}

extern "C" void kernel_launch(void* const* d_in, const int* in_sizes, int n_in,
                              void* d_out, int out_size, void* d_ws, size_t ws_size,
                              hipStream_t stream) {
  const float* node_feat = (const float*)d_in[0];
  const float* rel_emb   = (const float*)d_in[1];
  const int*   src       = (const int*)d_in[2];
  const int*   dst       = (const int*)d_in[3];
  const int*   etype     = (const int*)d_in[4];
  const int*   direction = (const int*)d_in[5];
  const float* W_self    = (const float*)d_in[6];
  const float* W_forward = (const float*)d_in[7];
  // d_in[8] = W_backward (unused: backward edges contribute zero)
  const float* W_rel     = (const float*)d_in[9];
  const float* bias      = (const float*)d_in[10];

  int n_nodes = in_sizes[0] / D;
  int n_rel   = in_sizes[1] / D;
  int n_edges = in_sizes[2];

  float* out     = (float*)d_out;
  float* rel_out = out + (size_t)n_nodes * D;

  // ws layout
  char* ws = (char*)d_ws;
  size_t offX = 0;
  size_t offR = offX + (size_t)n_nodes * D * 4;
  size_t offCur = offR + (size_t)n_rel * D * 4;
  size_t offSums = offCur + (size_t)n_nodes * 4;
  size_t offPerm = offSums + 1024 * 4;
  size_t need = offPerm + (size_t)n_edges * 4;

  float* X = (float*)(ws + offX);
  float* R = (float*)(ws + offR);
  int* cursor = (int*)(ws + offCur);
  int* sums = (int*)(ws + offSums);
  int* perm = (int*)(ws + offPerm);

  // 1) R and rel_out
  rel_kernel<<<50, 256, 0, stream>>>(rel_emb, W_forward, W_rel, R, rel_out, n_rel);

  // 2) out = nf@Ws^T + bias ; X = nf@Wf^T  (single fused pass, W pinned in VGPR)
  node_fused<<<1024, 256, 0, stream>>>(node_feat, W_self, W_forward, bias,
                                       out, X, n_nodes);

  if (ws_size >= need) {
    int nblk = (n_nodes + SCAN_CHUNK - 1) / SCAN_CHUNK;
    k_zero<<<256, 256, 0, stream>>>(cursor, n_nodes + 1024);
    k_hist<<<1024, 256, 0, stream>>>(dst, direction, cursor, n_edges);
    k_sums<<<nblk, 256, 0, stream>>>(cursor, sums, n_nodes);
    k_scan_sums<<<1, 1024, 0, stream>>>(sums, nblk);
    k_scan_chunks<<<nblk, 256, 0, stream>>>(cursor, sums, n_nodes);
    k_scatter<<<1024, 256, 0, stream>>>(dst, direction, cursor, perm, n_edges);
    k_gather<<<2048, 256, 0, stream>>>(cursor, perm, src, etype, X, R, out, n_nodes);
  } else {
    edge_atomic<<<2048, 256, 0, stream>>>(src, dst, etype, direction, X, R, out,
                                          n_edges);
  }
}

// Round 5
// 212.375 us; speedup vs baseline: 3.9701x; 3.9701x over previous
//
#include <hip/hip_runtime.h>

#define D 64
#define SCAN_CHUNK 1024

// ---------------- rel kernel: R = rel_emb @ Wf^T ; rel_out = rel_emb @ Wrel^T
__global__ __launch_bounds__(256) void rel_kernel(
    const float* __restrict__ rel_emb,
    const float* __restrict__ W_f,
    const float* __restrict__ W_rel,
    float* __restrict__ R,
    float* __restrict__ rel_out,
    int n_rel) {
  __shared__ float WtF[D][D];
  __shared__ float WtR[D][D];
  int tid = threadIdx.x;
  for (int idx = tid; idx < D * D; idx += 256) {
    int j = idx >> 6, k = idx & 63;
    WtF[k][j] = W_f[idx];
    WtR[k][j] = W_rel[idx];
  }
  __syncthreads();
  int lane = tid & 63, wave = tid >> 6;
  for (int r = blockIdx.x * 4 + wave; r < n_rel; r += gridDim.x * 4) {
    const float4* a = (const float4*)(rel_emb + (size_t)r * D);
    float accR = 0.f, accO = 0.f;
#pragma unroll
    for (int k4 = 0; k4 < 16; ++k4) {
      float4 av = a[k4];
      int k = k4 * 4;
      accR += av.x * WtF[k][lane] + av.y * WtF[k + 1][lane] +
              av.z * WtF[k + 2][lane] + av.w * WtF[k + 3][lane];
      accO += av.x * WtR[k][lane] + av.y * WtR[k + 1][lane] +
              av.z * WtR[k + 2][lane] + av.w * WtR[k + 3][lane];
    }
    R[(size_t)r * D + lane] = accR;
    rel_out[(size_t)r * D + lane] = accO;
  }
}

// ---------------- fused node GEMV: out = nf@Ws^T + bias ; X = nf@Wf^T
// W in LDS (structural residency -- the compiler can neither rematerialize nor
// spill it; R3/R4 failure modes). Layout: LW[j][k4 ^ (j&7)] float4 -- the
// guide's 256B-row XOR swizzle, so lane j's ds_read_b128 of its own row is
// conflict-free. Each W read amortized over 4 rows (A via wave-uniform
// broadcast float4 loads).
__global__ __launch_bounds__(256) void node_fused(
    const float* __restrict__ nf,
    const float* __restrict__ W_self,
    const float* __restrict__ W_f,
    const float* __restrict__ bias,
    float* __restrict__ out,
    float* __restrict__ X,
    int n_nodes) {
  __shared__ float4 LWs[64][16];
  __shared__ float4 LWf[64][16];
  int tid = threadIdx.x;
  for (int q = tid; q < 1024; q += 256) {
    int j = q >> 4, k4 = q & 15;
    int sk = k4 ^ (j & 7);
    LWs[j][sk] = ((const float4*)W_self)[q];
    LWf[j][sk] = ((const float4*)W_f)[q];
  }
  int lane = tid & 63;
  float b = bias[lane];
  __syncthreads();

  int wave_id = (int)((blockIdx.x * blockDim.x + tid) >> 6);
  int n_waves = (int)((gridDim.x * blockDim.x) >> 6);
  int ngroups = (n_nodes + 3) >> 2;

  for (int g = wave_id; g < ngroups; g += n_waves) {
    int row0 = g << 2;
    int r1 = min(row0 + 1, n_nodes - 1);
    int r2 = min(row0 + 2, n_nodes - 1);
    int r3 = min(row0 + 3, n_nodes - 1);
    const float4* a0 = (const float4*)(nf + (size_t)row0 * D);
    const float4* a1 = (const float4*)(nf + (size_t)r1 * D);
    const float4* a2 = (const float4*)(nf + (size_t)r2 * D);
    const float4* a3 = (const float4*)(nf + (size_t)r3 * D);
    float s0 = 0.f, s1 = 0.f, s2 = 0.f, s3 = 0.f;
    float f0 = 0.f, f1 = 0.f, f2 = 0.f, f3 = 0.f;
#pragma unroll
    for (int k4 = 0; k4 < 16; ++k4) {
      int sk = k4 ^ (lane & 7);
      float4 wq = LWs[lane][sk];   // ds_read_b128, conflict-free (swizzled)
      float4 vq = LWf[lane][sk];
      float4 A0 = a0[k4];          // wave-uniform addr -> broadcast
      float4 A1 = a1[k4];
      float4 A2 = a2[k4];
      float4 A3 = a3[k4];
      s0 += A0.x * wq.x + A0.y * wq.y + A0.z * wq.z + A0.w * wq.w;
      f0 += A0.x * vq.x + A0.y * vq.y + A0.z * vq.z + A0.w * vq.w;
      s1 += A1.x * wq.x + A1.y * wq.y + A1.z * wq.z + A1.w * wq.w;
      f1 += A1.x * vq.x + A1.y * vq.y + A1.z * vq.z + A1.w * vq.w;
      s2 += A2.x * wq.x + A2.y * wq.y + A2.z * wq.z + A2.w * wq.w;
      f2 += A2.x * vq.x + A2.y * vq.y + A2.z * vq.z + A2.w * vq.w;
      s3 += A3.x * wq.x + A3.y * wq.y + A3.z * wq.z + A3.w * wq.w;
      f3 += A3.x * vq.x + A3.y * vq.y + A3.z * vq.z + A3.w * vq.w;
    }
    size_t o0 = (size_t)row0 * D + lane;
    out[o0] = s0 + b;
    X[o0] = f0;
    if (row0 + 1 < n_nodes) { out[o0 + D] = s1 + b;     X[o0 + D] = f1; }
    if (row0 + 2 < n_nodes) { out[o0 + 2 * D] = s2 + b; X[o0 + 2 * D] = f2; }
    if (row0 + 3 < n_nodes) { out[o0 + 3 * D] = s3 + b; X[o0 + 3 * D] = f3; }
  }
}

// ---------------- CSR build ----------------
__global__ __launch_bounds__(256) void k_zero(int* __restrict__ p, int n) {
  int i = blockIdx.x * blockDim.x + threadIdx.x;
  int stride = gridDim.x * blockDim.x;
  for (; i < n; i += stride) p[i] = 0;
}

__global__ __launch_bounds__(256) void k_hist(
    const int* __restrict__ dst, const int* __restrict__ dir,
    int* __restrict__ cnt, int n_edges) {
  int i = blockIdx.x * blockDim.x + threadIdx.x;
  int stride = gridDim.x * blockDim.x;
  for (; i < n_edges; i += stride)
    if (dir[i] == 0) atomicAdd(&cnt[dst[i]], 1);
}

__global__ __launch_bounds__(256) void k_sums(
    const int* __restrict__ cnt, int* __restrict__ sums, int n) {
  __shared__ int ws_[4];
  int b = blockIdx.x, t = threadIdx.x;
  int lane = t & 63, wave = t >> 6;
  int s = 0;
  for (int j = 0; j < 4; ++j) {
    int i = b * SCAN_CHUNK + t * 4 + j;
    if (i < n) s += cnt[i];
  }
  for (int off = 32; off; off >>= 1) s += __shfl_down(s, off);
  if (lane == 0) ws_[wave] = s;
  __syncthreads();
  if (t == 0) sums[b] = ws_[0] + ws_[1] + ws_[2] + ws_[3];
}

__global__ __launch_bounds__(1024) void k_scan_sums(int* __restrict__ sums, int nblk) {
  __shared__ int l[1024];
  int t = threadIdx.x;
  l[t] = (t < nblk) ? sums[t] : 0;
  __syncthreads();
  for (int d = 1; d < 1024; d <<= 1) {
    int v = (t >= d) ? l[t - d] : 0;
    __syncthreads();
    l[t] += v;
    __syncthreads();
  }
  if (t < nblk) sums[t] = (t == 0) ? 0 : l[t - 1];
}

__global__ __launch_bounds__(256) void k_scan_chunks(
    int* __restrict__ cnt, const int* __restrict__ sums, int n) {
  __shared__ int wsum[4];
  int b = blockIdx.x, t = threadIdx.x;
  int lane = t & 63, wave = t >> 6;
  int i0 = b * SCAN_CHUNK + t * 4;
  int c0 = (i0 + 0 < n) ? cnt[i0 + 0] : 0;
  int c1 = (i0 + 1 < n) ? cnt[i0 + 1] : 0;
  int c2 = (i0 + 2 < n) ? cnt[i0 + 2] : 0;
  int c3 = (i0 + 3 < n) ? cnt[i0 + 3] : 0;
  int s = c0 + c1 + c2 + c3;
  int inc = s;
  for (int d = 1; d < 64; d <<= 1) {
    int v = __shfl_up(inc, d);
    if (lane >= d) inc += v;
  }
  if (lane == 63) wsum[wave] = inc;
  __syncthreads();
  int wbase = 0;
  if (wave > 0) wbase += wsum[0];
  if (wave > 1) wbase += wsum[1];
  if (wave > 2) wbase += wsum[2];
  int ex = sums[b] + wbase + inc - s;
  if (i0 + 0 < n) cnt[i0 + 0] = ex;
  if (i0 + 1 < n) cnt[i0 + 1] = ex + c0;
  if (i0 + 2 < n) cnt[i0 + 2] = ex + c0 + c1;
  if (i0 + 3 < n) cnt[i0 + 3] = ex + c0 + c1 + c2;
}

__global__ __launch_bounds__(256) void k_scatter(
    const int* __restrict__ dst, const int* __restrict__ dir,
    int* __restrict__ cursor, int* __restrict__ perm, int n_edges) {
  int i = blockIdx.x * blockDim.x + threadIdx.x;
  int stride = gridDim.x * blockDim.x;
  for (; i < n_edges; i += stride)
    if (dir[i] == 0) {
      int pos = atomicAdd(&cursor[dst[i]], 1);
      perm[pos] = i;
    }
}

// ---------------- gather: out[n] += sum_{e in bucket(n)} X[src[e]] - R[et[e]]
__global__ __launch_bounds__(256) void k_gather(
    const int* __restrict__ cursor, const int* __restrict__ perm,
    const int* __restrict__ src, const int* __restrict__ etype,
    const float* __restrict__ X, const float* __restrict__ R,
    float* __restrict__ out, int n_nodes) {
  int lane = threadIdx.x & 63;
  int wave_id = (int)((blockIdx.x * blockDim.x + threadIdx.x) >> 6);
  int n_waves = (int)((gridDim.x * blockDim.x) >> 6);
  for (int node = wave_id; node < n_nodes; node += n_waves) {
    int end = cursor[node];
    int beg = (node == 0) ? 0 : cursor[node - 1];
    if (end <= beg) continue;
    float acc = 0.f;
    int k = beg;
    for (; k + 1 < end; k += 2) {
      int e0 = perm[k], e1 = perm[k + 1];
      int s0 = src[e0], t0 = etype[e0];
      int s1 = src[e1], t1 = etype[e1];
      float a0 = X[(size_t)s0 * D + lane] - R[(size_t)t0 * D + lane];
      float a1 = X[(size_t)s1 * D + lane] - R[(size_t)t1 * D + lane];
      acc += a0 + a1;
    }
    if (k < end) {
      int e0 = perm[k];
      acc += X[(size_t)src[e0] * D + lane] - R[(size_t)etype[e0] * D + lane];
    }
    out[(size_t)node * D + lane] += acc;
  }
}

// ---------------- fallback edge kernel (atomic) ----------------
__global__ __launch_bounds__(256) void edge_atomic(
    const int* __restrict__ src, const int* __restrict__ dst,
    const int* __restrict__ et, const int* __restrict__ dir,
    const float* __restrict__ X, const float* __restrict__ R,
    float* __restrict__ out, int n_edges) {
  int lane = threadIdx.x & 63;
  long long wave_id = ((long long)blockIdx.x * blockDim.x + threadIdx.x) >> 6;
  long long n_waves = ((long long)gridDim.x * blockDim.x) >> 6;
  for (long long base = wave_id * 64; base < n_edges; base += n_waves * 64) {
    int e = (int)base + lane;
    int s_l = 0, d_l = 0, t_l = 0, dir_l = 1;
    if (e < n_edges) {
      s_l = src[e]; d_l = dst[e]; t_l = et[e]; dir_l = dir[e];
    }
    int cnt = min(64, n_edges - (int)base);
    for (int i = 0; i < cnt; ++i) {
      int dir_i = __shfl(dir_l, i);
      if (dir_i != 0) continue;
      int s_i = __shfl(s_l, i);
      int t_i = __shfl(t_l, i);
      int d_i = __shfl(d_l, i);
      float val = X[(size_t)s_i * D + lane] - R[(size_t)t_i * D + lane];
      atomicAdd(&out[(size_t)d_i * D + lane], val);
    }
  }
}

extern "C" void kernel_launch(void* const* d_in, const int* in_sizes, int n_in,
                              void* d_out, int out_size, void* d_ws, size_t ws_size,
                              hipStream_t stream) {
  const float* node_feat = (const float*)d_in[0];
  const float* rel_emb   = (const float*)d_in[1];
  const int*   src       = (const int*)d_in[2];
  const int*   dst       = (const int*)d_in[3];
  const int*   etype     = (const int*)d_in[4];
  const int*   direction = (const int*)d_in[5];
  const float* W_self    = (const float*)d_in[6];
  const float* W_forward = (const float*)d_in[7];
  // d_in[8] = W_backward (unused: backward edges contribute zero)
  const float* W_rel     = (const float*)d_in[9];
  const float* bias      = (const float*)d_in[10];

  int n_nodes = in_sizes[0] / D;
  int n_rel   = in_sizes[1] / D;
  int n_edges = in_sizes[2];

  float* out     = (float*)d_out;
  float* rel_out = out + (size_t)n_nodes * D;

  // ws layout
  char* ws = (char*)d_ws;
  size_t offX = 0;
  size_t offR = offX + (size_t)n_nodes * D * 4;
  size_t offCur = offR + (size_t)n_rel * D * 4;
  size_t offSums = offCur + (size_t)n_nodes * 4;
  size_t offPerm = offSums + 1024 * 4;
  size_t need = offPerm + (size_t)n_edges * 4;

  float* X = (float*)(ws + offX);
  float* R = (float*)(ws + offR);
  int* cursor = (int*)(ws + offCur);
  int* sums = (int*)(ws + offSums);
  int* perm = (int*)(ws + offPerm);

  // 1) R and rel_out
  rel_kernel<<<50, 256, 0, stream>>>(rel_emb, W_forward, W_rel, R, rel_out, n_rel);

  // 2) out = nf@Ws^T + bias ; X = nf@Wf^T  (fused, W in swizzled LDS)
  node_fused<<<1024, 256, 0, stream>>>(node_feat, W_self, W_forward, bias,
                                       out, X, n_nodes);

  if (ws_size >= need) {
    int nblk = (n_nodes + SCAN_CHUNK - 1) / SCAN_CHUNK;
    k_zero<<<256, 256, 0, stream>>>(cursor, n_nodes + 1024);
    k_hist<<<1024, 256, 0, stream>>>(dst, direction, cursor, n_edges);
    k_sums<<<nblk, 256, 0, stream>>>(cursor, sums, n_nodes);
    k_scan_sums<<<1, 1024, 0, stream>>>(sums, nblk);
    k_scan_chunks<<<nblk, 256, 0, stream>>>(cursor, sums, n_nodes);
    k_scatter<<<1024, 256, 0, stream>>>(dst, direction, cursor, perm, n_edges);
    k_gather<<<2048, 256, 0, stream>>>(cursor, perm, src, etype, X, R, out, n_nodes);
  } else {
    edge_atomic<<<2048, 256, 0, stream>>>(src, dst, etype, direction, X, R, out,
                                          n_edges);
  }
}

// Round 6
// 173.289 us; speedup vs baseline: 4.8656x; 1.2256x over previous
//
#include <hip/hip_runtime.h>

#define D 64
#define SCAN_CHUNK 1024

// ---------------- rel kernel: R = rel_emb @ Wf^T ; rel_out = rel_emb @ Wrel^T
__global__ __launch_bounds__(256) void rel_kernel(
    const float* __restrict__ rel_emb,
    const float* __restrict__ W_f,
    const float* __restrict__ W_rel,
    float* __restrict__ R,
    float* __restrict__ rel_out,
    int n_rel) {
  __shared__ float WtF[D][D];
  __shared__ float WtR[D][D];
  int tid = threadIdx.x;
  for (int idx = tid; idx < D * D; idx += 256) {
    int j = idx >> 6, k = idx & 63;
    WtF[k][j] = W_f[idx];
    WtR[k][j] = W_rel[idx];
  }
  __syncthreads();
  int lane = tid & 63, wave = tid >> 6;
  for (int r = blockIdx.x * 4 + wave; r < n_rel; r += gridDim.x * 4) {
    const float4* a = (const float4*)(rel_emb + (size_t)r * D);
    float accR = 0.f, accO = 0.f;
#pragma unroll
    for (int k4 = 0; k4 < 16; ++k4) {
      float4 av = a[k4];
      int k = k4 * 4;
      accR += av.x * WtF[k][lane] + av.y * WtF[k + 1][lane] +
              av.z * WtF[k + 2][lane] + av.w * WtF[k + 3][lane];
      accO += av.x * WtR[k][lane] + av.y * WtR[k + 1][lane] +
              av.z * WtR[k + 2][lane] + av.w * WtR[k + 3][lane];
    }
    R[(size_t)r * D + lane] = accR;
    rel_out[(size_t)r * D + lane] = accO;
  }
}

// ---------------- fused node GEMV: out = nf@Ws^T + bias ; X = nf@Wf^T
// W in swizzled LDS (structural residency; R3=remat, R4=spill failure modes).
// R5 lesson: full unroll -> VGPR 220 -> 2 waves/SIMD -> latency-bound at 96us.
// unroll 4 keeps ~16 A-float4 in flight -> VGPR ~100 -> 4-5 waves/SIMD.
__global__ __launch_bounds__(256) void node_fused(
    const float* __restrict__ nf,
    const float* __restrict__ W_self,
    const float* __restrict__ W_f,
    const float* __restrict__ bias,
    float* __restrict__ out,
    float* __restrict__ X,
    int n_nodes) {
  __shared__ float4 LWs[64][16];
  __shared__ float4 LWf[64][16];
  int tid = threadIdx.x;
  for (int q = tid; q < 1024; q += 256) {
    int j = q >> 4, k4 = q & 15;
    int sk = k4 ^ (j & 7);
    LWs[j][sk] = ((const float4*)W_self)[q];
    LWf[j][sk] = ((const float4*)W_f)[q];
  }
  int lane = tid & 63;
  float b = bias[lane];
  __syncthreads();

  int wave_id = (int)((blockIdx.x * blockDim.x + tid) >> 6);
  int n_waves = (int)((gridDim.x * blockDim.x) >> 6);
  int ngroups = (n_nodes + 3) >> 2;

  for (int g = wave_id; g < ngroups; g += n_waves) {
    int row0 = g << 2;
    int r1 = min(row0 + 1, n_nodes - 1);
    int r2 = min(row0 + 2, n_nodes - 1);
    int r3 = min(row0 + 3, n_nodes - 1);
    const float4* a0 = (const float4*)(nf + (size_t)row0 * D);
    const float4* a1 = (const float4*)(nf + (size_t)r1 * D);
    const float4* a2 = (const float4*)(nf + (size_t)r2 * D);
    const float4* a3 = (const float4*)(nf + (size_t)r3 * D);
    float s0 = 0.f, s1 = 0.f, s2 = 0.f, s3 = 0.f;
    float f0 = 0.f, f1 = 0.f, f2 = 0.f, f3 = 0.f;
#pragma unroll 4
    for (int k4 = 0; k4 < 16; ++k4) {
      int sk = k4 ^ (lane & 7);
      float4 wq = LWs[lane][sk];   // ds_read_b128, conflict-free (swizzled)
      float4 vq = LWf[lane][sk];
      float4 A0 = a0[k4];          // wave-uniform addr -> broadcast
      float4 A1 = a1[k4];
      float4 A2 = a2[k4];
      float4 A3 = a3[k4];
      s0 += A0.x * wq.x + A0.y * wq.y + A0.z * wq.z + A0.w * wq.w;
      f0 += A0.x * vq.x + A0.y * vq.y + A0.z * vq.z + A0.w * vq.w;
      s1 += A1.x * wq.x + A1.y * wq.y + A1.z * wq.z + A1.w * wq.w;
      f1 += A1.x * vq.x + A1.y * vq.y + A1.z * vq.z + A1.w * vq.w;
      s2 += A2.x * wq.x + A2.y * wq.y + A2.z * wq.z + A2.w * wq.w;
      f2 += A2.x * vq.x + A2.y * vq.y + A2.z * vq.z + A2.w * vq.w;
      s3 += A3.x * wq.x + A3.y * wq.y + A3.z * wq.z + A3.w * wq.w;
      f3 += A3.x * vq.x + A3.y * vq.y + A3.z * vq.z + A3.w * vq.w;
    }
    size_t o0 = (size_t)row0 * D + lane;
    out[o0] = s0 + b;
    X[o0] = f0;
    if (row0 + 1 < n_nodes) { out[o0 + D] = s1 + b;     X[o0 + D] = f1; }
    if (row0 + 2 < n_nodes) { out[o0 + 2 * D] = s2 + b; X[o0 + 2 * D] = f2; }
    if (row0 + 3 < n_nodes) { out[o0 + 3 * D] = s3 + b; X[o0 + 3 * D] = f3; }
  }
}

// ---------------- CSR build ----------------
__global__ __launch_bounds__(256) void k_zero(int* __restrict__ p, int n) {
  int i = blockIdx.x * blockDim.x + threadIdx.x;
  int stride = gridDim.x * blockDim.x;
  for (; i < n; i += stride) p[i] = 0;
}

__global__ __launch_bounds__(256) void k_hist(
    const int* __restrict__ dst, const int* __restrict__ dir,
    int* __restrict__ cnt, int n_edges) {
  int i = blockIdx.x * blockDim.x + threadIdx.x;
  int stride = gridDim.x * blockDim.x;
  for (; i < n_edges; i += stride)
    if (dir[i] == 0) atomicAdd(&cnt[dst[i]], 1);
}

__global__ __launch_bounds__(256) void k_sums(
    const int* __restrict__ cnt, int* __restrict__ sums, int n) {
  __shared__ int ws_[4];
  int b = blockIdx.x, t = threadIdx.x;
  int lane = t & 63, wave = t >> 6;
  int s = 0;
  for (int j = 0; j < 4; ++j) {
    int i = b * SCAN_CHUNK + t * 4 + j;
    if (i < n) s += cnt[i];
  }
  for (int off = 32; off; off >>= 1) s += __shfl_down(s, off);
  if (lane == 0) ws_[wave] = s;
  __syncthreads();
  if (t == 0) sums[b] = ws_[0] + ws_[1] + ws_[2] + ws_[3];
}

__global__ __launch_bounds__(1024) void k_scan_sums(int* __restrict__ sums, int nblk) {
  __shared__ int l[1024];
  int t = threadIdx.x;
  l[t] = (t < nblk) ? sums[t] : 0;
  __syncthreads();
  for (int d = 1; d < 1024; d <<= 1) {
    int v = (t >= d) ? l[t - d] : 0;
    __syncthreads();
    l[t] += v;
    __syncthreads();
  }
  if (t < nblk) sums[t] = (t == 0) ? 0 : l[t - 1];
}

__global__ __launch_bounds__(256) void k_scan_chunks(
    int* __restrict__ cnt, const int* __restrict__ sums, int n) {
  __shared__ int wsum[4];
  int b = blockIdx.x, t = threadIdx.x;
  int lane = t & 63, wave = t >> 6;
  int i0 = b * SCAN_CHUNK + t * 4;
  int c0 = (i0 + 0 < n) ? cnt[i0 + 0] : 0;
  int c1 = (i0 + 1 < n) ? cnt[i0 + 1] : 0;
  int c2 = (i0 + 2 < n) ? cnt[i0 + 2] : 0;
  int c3 = (i0 + 3 < n) ? cnt[i0 + 3] : 0;
  int s = c0 + c1 + c2 + c3;
  int inc = s;
  for (int d = 1; d < 64; d <<= 1) {
    int v = __shfl_up(inc, d);
    if (lane >= d) inc += v;
  }
  if (lane == 63) wsum[wave] = inc;
  __syncthreads();
  int wbase = 0;
  if (wave > 0) wbase += wsum[0];
  if (wave > 1) wbase += wsum[1];
  if (wave > 2) wbase += wsum[2];
  int ex = sums[b] + wbase + inc - s;
  if (i0 + 0 < n) cnt[i0 + 0] = ex;
  if (i0 + 1 < n) cnt[i0 + 1] = ex + c0;
  if (i0 + 2 < n) cnt[i0 + 2] = ex + c0 + c1;
  if (i0 + 3 < n) cnt[i0 + 3] = ex + c0 + c1 + c2;
}

// scatter packed (src<<8)|etype  -- gather then reads ONE coalesced stream
__global__ __launch_bounds__(256) void k_scatter_packed(
    const int* __restrict__ src, const int* __restrict__ dst,
    const int* __restrict__ et, const int* __restrict__ dir,
    int* __restrict__ cursor, int* __restrict__ perm, int n_edges) {
  int i = blockIdx.x * blockDim.x + threadIdx.x;
  int stride = gridDim.x * blockDim.x;
  for (; i < n_edges; i += stride)
    if (dir[i] == 0) {
      int pos = atomicAdd(&cursor[dst[i]], 1);
      perm[pos] = (src[i] << 8) | et[i];
    }
}

// ---------------- gather: out[n] += sum_{e in bucket(n)} X[src[e]] - R[et[e]]
__global__ __launch_bounds__(256) void k_gather(
    const int* __restrict__ cursor, const int* __restrict__ perm,
    const float* __restrict__ X, const float* __restrict__ R,
    float* __restrict__ out, int n_nodes) {
  int lane = threadIdx.x & 63;
  int wave_id = (int)((blockIdx.x * blockDim.x + threadIdx.x) >> 6);
  int n_waves = (int)((gridDim.x * blockDim.x) >> 6);
  for (int node = wave_id; node < n_nodes; node += n_waves) {
    int end = cursor[node];
    int beg = (node == 0) ? 0 : cursor[node - 1];
    if (end <= beg) continue;
    float acc = 0.f;
    int k = beg;
    for (; k + 3 < end; k += 4) {  // 4-wide for MLP
      int p0 = perm[k], p1 = perm[k + 1], p2 = perm[k + 2], p3 = perm[k + 3];
      float a0 = X[(size_t)(p0 >> 8) * D + lane] - R[(size_t)(p0 & 255) * D + lane];
      float a1 = X[(size_t)(p1 >> 8) * D + lane] - R[(size_t)(p1 & 255) * D + lane];
      float a2 = X[(size_t)(p2 >> 8) * D + lane] - R[(size_t)(p2 & 255) * D + lane];
      float a3 = X[(size_t)(p3 >> 8) * D + lane] - R[(size_t)(p3 & 255) * D + lane];
      acc += (a0 + a1) + (a2 + a3);
    }
    for (; k < end; ++k) {
      int p = perm[k];
      acc += X[(size_t)(p >> 8) * D + lane] - R[(size_t)(p & 255) * D + lane];
    }
    out[(size_t)node * D + lane] += acc;
  }
}

// ---------------- fallback edge kernel (atomic) ----------------
__global__ __launch_bounds__(256) void edge_atomic(
    const int* __restrict__ src, const int* __restrict__ dst,
    const int* __restrict__ et, const int* __restrict__ dir,
    const float* __restrict__ X, const float* __restrict__ R,
    float* __restrict__ out, int n_edges) {
  int lane = threadIdx.x & 63;
  long long wave_id = ((long long)blockIdx.x * blockDim.x + threadIdx.x) >> 6;
  long long n_waves = ((long long)gridDim.x * blockDim.x) >> 6;
  for (long long base = wave_id * 64; base < n_edges; base += n_waves * 64) {
    int e = (int)base + lane;
    int s_l = 0, d_l = 0, t_l = 0, dir_l = 1;
    if (e < n_edges) {
      s_l = src[e]; d_l = dst[e]; t_l = et[e]; dir_l = dir[e];
    }
    int cnt = min(64, n_edges - (int)base);
    for (int i = 0; i < cnt; ++i) {
      int dir_i = __shfl(dir_l, i);
      if (dir_i != 0) continue;
      int s_i = __shfl(s_l, i);
      int t_i = __shfl(t_l, i);
      int d_i = __shfl(d_l, i);
      float val = X[(size_t)s_i * D + lane] - R[(size_t)t_i * D + lane];
      atomicAdd(&out[(size_t)d_i * D + lane], val);
    }
  }
}

extern "C" void kernel_launch(void* const* d_in, const int* in_sizes, int n_in,
                              void* d_out, int out_size, void* d_ws, size_t ws_size,
                              hipStream_t stream) {
  const float* node_feat = (const float*)d_in[0];
  const float* rel_emb   = (const float*)d_in[1];
  const int*   src       = (const int*)d_in[2];
  const int*   dst       = (const int*)d_in[3];
  const int*   etype     = (const int*)d_in[4];
  const int*   direction = (const int*)d_in[5];
  const float* W_self    = (const float*)d_in[6];
  const float* W_forward = (const float*)d_in[7];
  // d_in[8] = W_backward (unused: backward edges contribute zero)
  const float* W_rel     = (const float*)d_in[9];
  const float* bias      = (const float*)d_in[10];

  int n_nodes = in_sizes[0] / D;
  int n_rel   = in_sizes[1] / D;
  int n_edges = in_sizes[2];

  float* out     = (float*)d_out;
  float* rel_out = out + (size_t)n_nodes * D;

  // ws layout
  char* ws = (char*)d_ws;
  size_t offX = 0;
  size_t offR = offX + (size_t)n_nodes * D * 4;
  size_t offCur = offR + (size_t)n_rel * D * 4;
  size_t offSums = offCur + (size_t)n_nodes * 4;
  size_t offPerm = offSums + 1024 * 4;
  size_t need = offPerm + (size_t)n_edges * 4;

  float* X = (float*)(ws + offX);
  float* R = (float*)(ws + offR);
  int* cursor = (int*)(ws + offCur);
  int* sums = (int*)(ws + offSums);
  int* perm = (int*)(ws + offPerm);

  // 1) R and rel_out
  rel_kernel<<<50, 256, 0, stream>>>(rel_emb, W_forward, W_rel, R, rel_out, n_rel);

  // 2) out = nf@Ws^T + bias ; X = nf@Wf^T  (fused, W in swizzled LDS)
  node_fused<<<1280, 256, 0, stream>>>(node_feat, W_self, W_forward, bias,
                                       out, X, n_nodes);

  bool packed_ok = (n_rel <= 256) && (n_nodes < (1 << 23));
  if (ws_size >= need && packed_ok) {
    int nblk = (n_nodes + SCAN_CHUNK - 1) / SCAN_CHUNK;
    k_zero<<<256, 256, 0, stream>>>(cursor, n_nodes + 1024);
    k_hist<<<1024, 256, 0, stream>>>(dst, direction, cursor, n_edges);
    k_sums<<<nblk, 256, 0, stream>>>(cursor, sums, n_nodes);
    k_scan_sums<<<1, 1024, 0, stream>>>(sums, nblk);
    k_scan_chunks<<<nblk, 256, 0, stream>>>(cursor, sums, n_nodes);
    k_scatter_packed<<<1024, 256, 0, stream>>>(src, dst, etype, direction,
                                               cursor, perm, n_edges);
    k_gather<<<2048, 256, 0, stream>>>(cursor, perm, X, R, out, n_nodes);
  } else {
    edge_atomic<<<2048, 256, 0, stream>>>(src, dst, etype, direction, X, R, out,
                                          n_edges);
  }
}

// Round 7
// 152.041 us; speedup vs baseline: 5.5456x; 1.1397x over previous
//
#include <hip/hip_runtime.h>

#define D 64
#define SCAN_CHUNK 1024
#define TILE_ROWS 64

// ---------------- rel kernel: R = rel_emb @ Wf^T ; rel_out = rel_emb @ Wrel^T
__global__ __launch_bounds__(256) void rel_kernel(
    const float* __restrict__ rel_emb,
    const float* __restrict__ W_f,
    const float* __restrict__ W_rel,
    float* __restrict__ R,
    float* __restrict__ rel_out,
    int n_rel) {
  __shared__ float WtF[D][D];
  __shared__ float WtR[D][D];
  int tid = threadIdx.x;
  for (int idx = tid; idx < D * D; idx += 256) {
    int j = idx >> 6, k = idx & 63;
    WtF[k][j] = W_f[idx];
    WtR[k][j] = W_rel[idx];
  }
  __syncthreads();
  int lane = tid & 63, wave = tid >> 6;
  for (int r = blockIdx.x * 4 + wave; r < n_rel; r += gridDim.x * 4) {
    const float4* a = (const float4*)(rel_emb + (size_t)r * D);
    float accR = 0.f, accO = 0.f;
#pragma unroll
    for (int k4 = 0; k4 < 16; ++k4) {
      float4 av = a[k4];
      int k = k4 * 4;
      accR += av.x * WtF[k][lane] + av.y * WtF[k + 1][lane] +
              av.z * WtF[k + 2][lane] + av.w * WtF[k + 3][lane];
      accO += av.x * WtR[k][lane] + av.y * WtR[k + 1][lane] +
              av.z * WtR[k + 2][lane] + av.w * WtR[k + 3][lane];
    }
    R[(size_t)r * D + lane] = accR;
    rel_out[(size_t)r * D + lane] = accO;
  }
}

// ---------------- fused node GEMV: out = nf@Ws^T + bias ; X = nf@Wf^T
// v3: W in LDS as [k4][j] (lane j reads LW[k4][lane] -> 64 lanes sequential
// 1024B = ideal b128 pattern, zero conflicts by construction; R6's
// column-XOR swizzle still collided 8-way within b128 groups).
// A staged in 64-row LDS tiles via coalesced loads, software-pipelined
// (issue next tile's loads before computing current -> HBM latency hidden
// under ~2400cyc of compute). Compute reads A as same-address broadcasts.
__global__ __launch_bounds__(256) void node_fused(
    const float* __restrict__ nf,
    const float* __restrict__ W_self,
    const float* __restrict__ W_f,
    const float* __restrict__ bias,
    float* __restrict__ out,
    float* __restrict__ X,
    int n_nodes) {
  __shared__ float4 LWs[16][64];   // [k4][j]
  __shared__ float4 LWf[16][64];
  __shared__ float4 At[TILE_ROWS][16];

  int tid = threadIdx.x;
  // stage W: thread q2 -> k4=q2>>6, j=q2&63 ; sequential LDS writes
#pragma unroll
  for (int i = 0; i < 4; ++i) {
    int q2 = tid + 256 * i;
    int k4 = q2 >> 6, j = q2 & 63;
    LWs[k4][j] = ((const float4*)W_self)[j * 16 + k4];
    LWf[k4][j] = ((const float4*)W_f)[j * 16 + k4];
  }
  int lane = tid & 63;
  int wave = tid >> 6;
  float b = bias[lane];
  __syncthreads();

  int ntiles = (n_nodes + TILE_ROWS - 1) / TILE_ROWS;
  int tile = blockIdx.x;
  if (tile >= ntiles) return;

  // prefetch tile `tile` into regs (coalesced: thread covers qwords tid+256*i)
  float4 p0, p1, p2, p3;
  {
    int base = tile * TILE_ROWS;
    int q0 = tid, q1 = tid + 256, q2 = tid + 512, q3 = tid + 768;
    int r0 = min(base + (q0 >> 4), n_nodes - 1);
    int r1 = min(base + (q1 >> 4), n_nodes - 1);
    int r2 = min(base + (q2 >> 4), n_nodes - 1);
    int r3 = min(base + (q3 >> 4), n_nodes - 1);
    p0 = ((const float4*)nf)[(size_t)r0 * 16 + (q0 & 15)];
    p1 = ((const float4*)nf)[(size_t)r1 * 16 + (q1 & 15)];
    p2 = ((const float4*)nf)[(size_t)r2 * 16 + (q2 & 15)];
    p3 = ((const float4*)nf)[(size_t)r3 * 16 + (q3 & 15)];
  }

  while (tile < ntiles) {
    __syncthreads();   // previous compute done reading At
    // write staged regs -> LDS (sequential per lane)
    ((float4*)At)[tid]       = p0;
    ((float4*)At)[tid + 256] = p1;
    ((float4*)At)[tid + 512] = p2;
    ((float4*)At)[tid + 768] = p3;
    int nxt = tile + gridDim.x;
    __syncthreads();   // tile visible
    if (nxt < ntiles) {  // issue next tile's loads BEFORE compute (overlap)
      int base = nxt * TILE_ROWS;
      int q0 = tid, q1 = tid + 256, q2 = tid + 512, q3 = tid + 768;
      int r0 = min(base + (q0 >> 4), n_nodes - 1);
      int r1 = min(base + (q1 >> 4), n_nodes - 1);
      int r2 = min(base + (q2 >> 4), n_nodes - 1);
      int r3 = min(base + (q3 >> 4), n_nodes - 1);
      p0 = ((const float4*)nf)[(size_t)r0 * 16 + (q0 & 15)];
      p1 = ((const float4*)nf)[(size_t)r1 * 16 + (q1 & 15)];
      p2 = ((const float4*)nf)[(size_t)r2 * 16 + (q2 & 15)];
      p3 = ((const float4*)nf)[(size_t)r3 * 16 + (q3 & 15)];
    }

    // compute: wave handles rows [wave*16, wave*16+16), two groups of 8
    int row_base = tile * TILE_ROWS + wave * 16;
#pragma unroll
    for (int grp = 0; grp < 2; ++grp) {
      int lr = wave * 16 + grp * 8;   // local row base
      float s0 = 0.f, s1 = 0.f, s2 = 0.f, s3 = 0.f;
      float s4 = 0.f, s5 = 0.f, s6 = 0.f, s7 = 0.f;
      float f0 = 0.f, f1 = 0.f, f2 = 0.f, f3 = 0.f;
      float f4 = 0.f, f5 = 0.f, f6 = 0.f, f7 = 0.f;
#pragma unroll 4
      for (int k4 = 0; k4 < 16; ++k4) {
        float4 wq = LWs[k4][lane];   // sequential b128: conflict-free
        float4 vq = LWf[k4][lane];
        float4 A0 = At[lr + 0][k4];  // same-addr broadcast: free
        float4 A1 = At[lr + 1][k4];
        float4 A2 = At[lr + 2][k4];
        float4 A3 = At[lr + 3][k4];
        float4 A4 = At[lr + 4][k4];
        float4 A5 = At[lr + 5][k4];
        float4 A6 = At[lr + 6][k4];
        float4 A7 = At[lr + 7][k4];
        s0 += A0.x*wq.x + A0.y*wq.y + A0.z*wq.z + A0.w*wq.w;
        f0 += A0.x*vq.x + A0.y*vq.y + A0.z*vq.z + A0.w*vq.w;
        s1 += A1.x*wq.x + A1.y*wq.y + A1.z*wq.z + A1.w*wq.w;
        f1 += A1.x*vq.x + A1.y*vq.y + A1.z*vq.z + A1.w*vq.w;
        s2 += A2.x*wq.x + A2.y*wq.y + A2.z*wq.z + A2.w*wq.w;
        f2 += A2.x*vq.x + A2.y*vq.y + A2.z*vq.z + A2.w*vq.w;
        s3 += A3.x*wq.x + A3.y*wq.y + A3.z*wq.z + A3.w*wq.w;
        f3 += A3.x*vq.x + A3.y*vq.y + A3.z*vq.z + A3.w*vq.w;
        s4 += A4.x*wq.x + A4.y*wq.y + A4.z*wq.z + A4.w*wq.w;
        f4 += A4.x*vq.x + A4.y*vq.y + A4.z*vq.z + A4.w*vq.w;
        s5 += A5.x*wq.x + A5.y*wq.y + A5.z*wq.z + A5.w*wq.w;
        f5 += A5.x*vq.x + A5.y*vq.y + A5.z*vq.z + A5.w*vq.w;
        s6 += A6.x*wq.x + A6.y*wq.y + A6.z*wq.z + A6.w*wq.w;
        f6 += A6.x*vq.x + A6.y*vq.y + A6.z*vq.z + A6.w*vq.w;
        s7 += A7.x*wq.x + A7.y*wq.y + A7.z*wq.z + A7.w*wq.w;
        f7 += A7.x*vq.x + A7.y*vq.y + A7.z*vq.z + A7.w*vq.w;
      }
      int rg = row_base + grp * 8;
      size_t o = (size_t)rg * D + lane;
      if (rg + 7 < n_nodes) {
        out[o]       = s0 + b; X[o]       = f0;
        out[o + D]   = s1 + b; X[o + D]   = f1;
        out[o + 2*D] = s2 + b; X[o + 2*D] = f2;
        out[o + 3*D] = s3 + b; X[o + 3*D] = f3;
        out[o + 4*D] = s4 + b; X[o + 4*D] = f4;
        out[o + 5*D] = s5 + b; X[o + 5*D] = f5;
        out[o + 6*D] = s6 + b; X[o + 6*D] = f6;
        out[o + 7*D] = s7 + b; X[o + 7*D] = f7;
      } else {
        float sv[8] = {s0,s1,s2,s3,s4,s5,s6,s7};
        float fv[8] = {f0,f1,f2,f3,f4,f5,f6,f7};
#pragma unroll
        for (int r = 0; r < 8; ++r)
          if (rg + r < n_nodes) {
            out[o + (size_t)r * D] = sv[r] + b;
            X[o + (size_t)r * D] = fv[r];
          }
      }
    }
    tile = nxt;
  }
}

// ---------------- CSR build ----------------
__global__ __launch_bounds__(256) void k_zero(int* __restrict__ p, int n) {
  int i = blockIdx.x * blockDim.x + threadIdx.x;
  int stride = gridDim.x * blockDim.x;
  for (; i < n; i += stride) p[i] = 0;
}

__global__ __launch_bounds__(256) void k_hist(
    const int* __restrict__ dst, const int* __restrict__ dir,
    int* __restrict__ cnt, int n_edges) {
  int i = blockIdx.x * blockDim.x + threadIdx.x;
  int stride = gridDim.x * blockDim.x;
  for (; i < n_edges; i += stride)
    if (dir[i] == 0) atomicAdd(&cnt[dst[i]], 1);
}

__global__ __launch_bounds__(256) void k_sums(
    const int* __restrict__ cnt, int* __restrict__ sums, int n) {
  __shared__ int ws_[4];
  int b = blockIdx.x, t = threadIdx.x;
  int lane = t & 63, wave = t >> 6;
  int s = 0;
  for (int j = 0; j < 4; ++j) {
    int i = b * SCAN_CHUNK + t * 4 + j;
    if (i < n) s += cnt[i];
  }
  for (int off = 32; off; off >>= 1) s += __shfl_down(s, off);
  if (lane == 0) ws_[wave] = s;
  __syncthreads();
  if (t == 0) sums[b] = ws_[0] + ws_[1] + ws_[2] + ws_[3];
}

__global__ __launch_bounds__(1024) void k_scan_sums(int* __restrict__ sums, int nblk) {
  __shared__ int l[1024];
  int t = threadIdx.x;
  l[t] = (t < nblk) ? sums[t] : 0;
  __syncthreads();
  for (int d = 1; d < 1024; d <<= 1) {
    int v = (t >= d) ? l[t - d] : 0;
    __syncthreads();
    l[t] += v;
    __syncthreads();
  }
  if (t < nblk) sums[t] = (t == 0) ? 0 : l[t - 1];
}

__global__ __launch_bounds__(256) void k_scan_chunks(
    int* __restrict__ cnt, const int* __restrict__ sums, int n) {
  __shared__ int wsum[4];
  int b = blockIdx.x, t = threadIdx.x;
  int lane = t & 63, wave = t >> 6;
  int i0 = b * SCAN_CHUNK + t * 4;
  int c0 = (i0 + 0 < n) ? cnt[i0 + 0] : 0;
  int c1 = (i0 + 1 < n) ? cnt[i0 + 1] : 0;
  int c2 = (i0 + 2 < n) ? cnt[i0 + 2] : 0;
  int c3 = (i0 + 3 < n) ? cnt[i0 + 3] : 0;
  int s = c0 + c1 + c2 + c3;
  int inc = s;
  for (int d = 1; d < 64; d <<= 1) {
    int v = __shfl_up(inc, d);
    if (lane >= d) inc += v;
  }
  if (lane == 63) wsum[wave] = inc;
  __syncthreads();
  int wbase = 0;
  if (wave > 0) wbase += wsum[0];
  if (wave > 1) wbase += wsum[1];
  if (wave > 2) wbase += wsum[2];
  int ex = sums[b] + wbase + inc - s;
  if (i0 + 0 < n) cnt[i0 + 0] = ex;
  if (i0 + 1 < n) cnt[i0 + 1] = ex + c0;
  if (i0 + 2 < n) cnt[i0 + 2] = ex + c0 + c1;
  if (i0 + 3 < n) cnt[i0 + 3] = ex + c0 + c1 + c2;
}

// scatter packed (src<<8)|etype  -- gather then reads ONE coalesced stream
__global__ __launch_bounds__(256) void k_scatter_packed(
    const int* __restrict__ src, const int* __restrict__ dst,
    const int* __restrict__ et, const int* __restrict__ dir,
    int* __restrict__ cursor, int* __restrict__ perm, int n_edges) {
  int i = blockIdx.x * blockDim.x + threadIdx.x;
  int stride = gridDim.x * blockDim.x;
  for (; i < n_edges; i += stride)
    if (dir[i] == 0) {
      int pos = atomicAdd(&cursor[dst[i]], 1);
      perm[pos] = (src[i] << 8) | et[i];
    }
}

// ---------------- gather: out[n] += sum_{e in bucket(n)} X[src[e]] - R[et[e]]
__global__ __launch_bounds__(256) void k_gather(
    const int* __restrict__ cursor, const int* __restrict__ perm,
    const float* __restrict__ X, const float* __restrict__ R,
    float* __restrict__ out, int n_nodes) {
  int lane = threadIdx.x & 63;
  int wave_id = (int)((blockIdx.x * blockDim.x + threadIdx.x) >> 6);
  int n_waves = (int)((gridDim.x * blockDim.x) >> 6);
  for (int node = wave_id; node < n_nodes; node += n_waves) {
    int end = cursor[node];
    int beg = (node == 0) ? 0 : cursor[node - 1];
    if (end <= beg) continue;
    float acc = 0.f;
    int k = beg;
    for (; k + 3 < end; k += 4) {  // 4-wide for MLP
      int p0 = perm[k], p1 = perm[k + 1], p2 = perm[k + 2], p3 = perm[k + 3];
      float a0 = X[(size_t)(p0 >> 8) * D + lane] - R[(size_t)(p0 & 255) * D + lane];
      float a1 = X[(size_t)(p1 >> 8) * D + lane] - R[(size_t)(p1 & 255) * D + lane];
      float a2 = X[(size_t)(p2 >> 8) * D + lane] - R[(size_t)(p2 & 255) * D + lane];
      float a3 = X[(size_t)(p3 >> 8) * D + lane] - R[(size_t)(p3 & 255) * D + lane];
      acc += (a0 + a1) + (a2 + a3);
    }
    for (; k < end; ++k) {
      int p = perm[k];
      acc += X[(size_t)(p >> 8) * D + lane] - R[(size_t)(p & 255) * D + lane];
    }
    out[(size_t)node * D + lane] += acc;
  }
}

// ---------------- fallback edge kernel (atomic) ----------------
__global__ __launch_bounds__(256) void edge_atomic(
    const int* __restrict__ src, const int* __restrict__ dst,
    const int* __restrict__ et, const int* __restrict__ dir,
    const float* __restrict__ X, const float* __restrict__ R,
    float* __restrict__ out, int n_edges) {
  int lane = threadIdx.x & 63;
  long long wave_id = ((long long)blockIdx.x * blockDim.x + threadIdx.x) >> 6;
  long long n_waves = ((long long)gridDim.x * blockDim.x) >> 6;
  for (long long base = wave_id * 64; base < n_edges; base += n_waves * 64) {
    int e = (int)base + lane;
    int s_l = 0, d_l = 0, t_l = 0, dir_l = 1;
    if (e < n_edges) {
      s_l = src[e]; d_l = dst[e]; t_l = et[e]; dir_l = dir[e];
    }
    int cnt = min(64, n_edges - (int)base);
    for (int i = 0; i < cnt; ++i) {
      int dir_i = __shfl(dir_l, i);
      if (dir_i != 0) continue;
      int s_i = __shfl(s_l, i);
      int t_i = __shfl(t_l, i);
      int d_i = __shfl(d_l, i);
      float val = X[(size_t)s_i * D + lane] - R[(size_t)t_i * D + lane];
      atomicAdd(&out[(size_t)d_i * D + lane], val);
    }
  }
}

extern "C" void kernel_launch(void* const* d_in, const int* in_sizes, int n_in,
                              void* d_out, int out_size, void* d_ws, size_t ws_size,
                              hipStream_t stream) {
  const float* node_feat = (const float*)d_in[0];
  const float* rel_emb   = (const float*)d_in[1];
  const int*   src       = (const int*)d_in[2];
  const int*   dst       = (const int*)d_in[3];
  const int*   etype     = (const int*)d_in[4];
  const int*   direction = (const int*)d_in[5];
  const float* W_self    = (const float*)d_in[6];
  const float* W_forward = (const float*)d_in[7];
  // d_in[8] = W_backward (unused: backward edges contribute zero)
  const float* W_rel     = (const float*)d_in[9];
  const float* bias      = (const float*)d_in[10];

  int n_nodes = in_sizes[0] / D;
  int n_rel   = in_sizes[1] / D;
  int n_edges = in_sizes[2];

  float* out     = (float*)d_out;
  float* rel_out = out + (size_t)n_nodes * D;

  // ws layout
  char* ws = (char*)d_ws;
  size_t offX = 0;
  size_t offR = offX + (size_t)n_nodes * D * 4;
  size_t offCur = offR + (size_t)n_rel * D * 4;
  size_t offSums = offCur + (size_t)n_nodes * 4;
  size_t offPerm = offSums + 1024 * 4;
  size_t need = offPerm + (size_t)n_edges * 4;

  float* X = (float*)(ws + offX);
  float* R = (float*)(ws + offR);
  int* cursor = (int*)(ws + offCur);
  int* sums = (int*)(ws + offSums);
  int* perm = (int*)(ws + offPerm);

  // 1) R and rel_out
  rel_kernel<<<50, 256, 0, stream>>>(rel_emb, W_forward, W_rel, R, rel_out, n_rel);

  // 2) out = nf@Ws^T + bias ; X = nf@Wf^T  (LDS-tiled, pipelined)
  node_fused<<<768, 256, 0, stream>>>(node_feat, W_self, W_forward, bias,
                                      out, X, n_nodes);

  bool packed_ok = (n_rel <= 256) && (n_nodes < (1 << 23));
  if (ws_size >= need && packed_ok) {
    int nblk = (n_nodes + SCAN_CHUNK - 1) / SCAN_CHUNK;
    k_zero<<<256, 256, 0, stream>>>(cursor, n_nodes + 1024);
    k_hist<<<1024, 256, 0, stream>>>(dst, direction, cursor, n_edges);
    k_sums<<<nblk, 256, 0, stream>>>(cursor, sums, n_nodes);
    k_scan_sums<<<1, 1024, 0, stream>>>(sums, nblk);
    k_scan_chunks<<<nblk, 256, 0, stream>>>(cursor, sums, n_nodes);
    k_scatter_packed<<<1024, 256, 0, stream>>>(src, dst, etype, direction,
                                               cursor, perm, n_edges);
    k_gather<<<2048, 256, 0, stream>>>(cursor, perm, X, R, out, n_nodes);
  } else {
    edge_atomic<<<2048, 256, 0, stream>>>(src, dst, etype, direction, X, R, out,
                                          n_edges);
  }
}

// Round 8
// 151.811 us; speedup vs baseline: 5.5540x; 1.0015x over previous
//
#include <hip/hip_runtime.h>

#define D 64
#define SCAN_CHUNK 1024

// ---------------- rel kernel: R = rel_emb @ Wf^T ; rel_out = rel_emb @ Wrel^T
__global__ __launch_bounds__(256) void rel_kernel(
    const float* __restrict__ rel_emb,
    const float* __restrict__ W_f,
    const float* __restrict__ W_rel,
    float* __restrict__ R,
    float* __restrict__ rel_out,
    int n_rel) {
  __shared__ float WtF[D][D];
  __shared__ float WtR[D][D];
  int tid = threadIdx.x;
  for (int idx = tid; idx < D * D; idx += 256) {
    int j = idx >> 6, k = idx & 63;
    WtF[k][j] = W_f[idx];
    WtR[k][j] = W_rel[idx];
  }
  __syncthreads();
  int lane = tid & 63, wave = tid >> 6;
  for (int r = blockIdx.x * 4 + wave; r < n_rel; r += gridDim.x * 4) {
    const float4* a = (const float4*)(rel_emb + (size_t)r * D);
    float accR = 0.f, accO = 0.f;
#pragma unroll
    for (int k4 = 0; k4 < 16; ++k4) {
      float4 av = a[k4];
      int k = k4 * 4;
      accR += av.x * WtF[k][lane] + av.y * WtF[k + 1][lane] +
              av.z * WtF[k + 2][lane] + av.w * WtF[k + 3][lane];
      accO += av.x * WtR[k][lane] + av.y * WtR[k + 1][lane] +
              av.z * WtR[k + 2][lane] + av.w * WtR[k + 3][lane];
    }
    R[(size_t)r * D + lane] = accR;
    rel_out[(size_t)r * D + lane] = accO;
  }
}

// ---------------- fused node GEMV: out = nf@Ws^T + bias ; X = nf@Wf^T
// v4: W in LDS [k4][j] (sequential b128, 0 conflicts -- R7 verified).
// A via wave-uniform GLOBAL float4 loads (VMEM pipe, SGPR base + imm offset)
// -- R7 lesson: A-broadcasts through LDS saturate the per-CU LDS unit
// (10 b128/k4/grp x 12cyc > 64 FMA x 2cyc); moving A to VMEM makes the
// kernel VALU-bound (~10.4us floor).
__global__ __launch_bounds__(256, 4) void node_fused(
    const float* __restrict__ nf,
    const float* __restrict__ W_self,
    const float* __restrict__ W_f,
    const float* __restrict__ bias,
    float* __restrict__ out,
    float* __restrict__ X,
    int n_nodes) {
  __shared__ float4 LWs[16][64];   // [k4][j]
  __shared__ float4 LWf[16][64];
  int tid = threadIdx.x;
#pragma unroll
  for (int i = 0; i < 4; ++i) {
    int q = tid + 256 * i;
    int k4 = q >> 6, j = q & 63;
    LWs[k4][j] = ((const float4*)W_self)[j * 16 + k4];
    LWf[k4][j] = ((const float4*)W_f)[j * 16 + k4];
  }
  int lane = tid & 63;
  float b = bias[lane];
  __syncthreads();

  int wave_id = blockIdx.x * 4 + (tid >> 6);
  int n_waves = gridDim.x * 4;
  int ngroups = (n_nodes + 7) >> 3;

  for (int g = wave_id; g < ngroups; g += n_waves) {
    int base = __builtin_amdgcn_readfirstlane(g << 3);  // wave-uniform
    const float4* a = (const float4*)nf + (size_t)base * 16;

    if (base + 8 <= n_nodes) {
      float s0=0,s1=0,s2=0,s3=0,s4=0,s5=0,s6=0,s7=0;
      float f0=0,f1=0,f2=0,f3=0,f4=0,f5=0,f6=0,f7=0;
#pragma unroll 2
      for (int k4 = 0; k4 < 16; ++k4) {
        float4 wq = LWs[k4][lane];     // ds_read_b128 sequential: 0 conflicts
        float4 vq = LWf[k4][lane];
        float4 A0 = a[k4];             // SGPR base + imm offset: VMEM broadcast
        float4 A1 = a[16 + k4];
        float4 A2 = a[32 + k4];
        float4 A3 = a[48 + k4];
        float4 A4 = a[64 + k4];
        float4 A5 = a[80 + k4];
        float4 A6 = a[96 + k4];
        float4 A7 = a[112 + k4];
        s0 += A0.x*wq.x + A0.y*wq.y + A0.z*wq.z + A0.w*wq.w;
        f0 += A0.x*vq.x + A0.y*vq.y + A0.z*vq.z + A0.w*vq.w;
        s1 += A1.x*wq.x + A1.y*wq.y + A1.z*wq.z + A1.w*wq.w;
        f1 += A1.x*vq.x + A1.y*vq.y + A1.z*vq.z + A1.w*vq.w;
        s2 += A2.x*wq.x + A2.y*wq.y + A2.z*wq.z + A2.w*wq.w;
        f2 += A2.x*vq.x + A2.y*vq.y + A2.z*vq.z + A2.w*vq.w;
        s3 += A3.x*wq.x + A3.y*wq.y + A3.z*wq.z + A3.w*wq.w;
        f3 += A3.x*vq.x + A3.y*vq.y + A3.z*vq.z + A3.w*vq.w;
        s4 += A4.x*wq.x + A4.y*wq.y + A4.z*wq.z + A4.w*wq.w;
        f4 += A4.x*vq.x + A4.y*vq.y + A4.z*vq.z + A4.w*vq.w;
        s5 += A5.x*wq.x + A5.y*wq.y + A5.z*wq.z + A5.w*wq.w;
        f5 += A5.x*vq.x + A5.y*vq.y + A5.z*vq.z + A5.w*vq.w;
        s6 += A6.x*wq.x + A6.y*wq.y + A6.z*wq.z + A6.w*wq.w;
        f6 += A6.x*vq.x + A6.y*vq.y + A6.z*vq.z + A6.w*vq.w;
        s7 += A7.x*wq.x + A7.y*wq.y + A7.z*wq.z + A7.w*wq.w;
        f7 += A7.x*vq.x + A7.y*vq.y + A7.z*vq.z + A7.w*vq.w;
      }
      size_t o = (size_t)base * D + lane;
      out[o]       = s0 + b; X[o]       = f0;
      out[o + D]   = s1 + b; X[o + D]   = f1;
      out[o + 2*D] = s2 + b; X[o + 2*D] = f2;
      out[o + 3*D] = s3 + b; X[o + 3*D] = f3;
      out[o + 4*D] = s4 + b; X[o + 4*D] = f4;
      out[o + 5*D] = s5 + b; X[o + 5*D] = f5;
      out[o + 6*D] = s6 + b; X[o + 6*D] = f6;
      out[o + 7*D] = s7 + b; X[o + 7*D] = f7;
    } else {
      for (int r = 0; r < 8; ++r) {
        int row = base + r;
        if (row >= n_nodes) break;
        const float4* ar = (const float4*)nf + (size_t)row * 16;
        float ss = 0.f, ff = 0.f;
#pragma unroll 4
        for (int k4 = 0; k4 < 16; ++k4) {
          float4 wq = LWs[k4][lane];
          float4 vq = LWf[k4][lane];
          float4 A = ar[k4];
          ss += A.x*wq.x + A.y*wq.y + A.z*wq.z + A.w*wq.w;
          ff += A.x*vq.x + A.y*vq.y + A.z*vq.z + A.w*vq.w;
        }
        out[(size_t)row * D + lane] = ss + b;
        X[(size_t)row * D + lane] = ff;
      }
    }
  }
}

// ---------------- CSR build ----------------
__global__ __launch_bounds__(256) void k_hist(
    const int* __restrict__ dst, const int* __restrict__ dir,
    int* __restrict__ cnt, int n_edges) {
  int i = blockIdx.x * blockDim.x + threadIdx.x;
  int stride = gridDim.x * blockDim.x;
  for (; i < n_edges; i += stride)
    if (dir[i] == 0) atomicAdd(&cnt[dst[i]], 1);
}

__global__ __launch_bounds__(256) void k_sums(
    const int* __restrict__ cnt, int* __restrict__ sums, int n) {
  __shared__ int ws_[4];
  int b = blockIdx.x, t = threadIdx.x;
  int lane = t & 63, wave = t >> 6;
  int s = 0;
  for (int j = 0; j < 4; ++j) {
    int i = b * SCAN_CHUNK + t * 4 + j;
    if (i < n) s += cnt[i];
  }
  for (int off = 32; off; off >>= 1) s += __shfl_down(s, off);
  if (lane == 0) ws_[wave] = s;
  __syncthreads();
  if (t == 0) sums[b] = ws_[0] + ws_[1] + ws_[2] + ws_[3];
}

// local scan of chunk + on-the-fly block offset (redundant reduce of <=~100
// chunk totals per block -- replaces the separate k_scan_sums launch)
__global__ __launch_bounds__(256) void k_scan_chunks(
    int* __restrict__ cnt, const int* __restrict__ sums, int n) {
  __shared__ int wsum[4];
  __shared__ int off_s;
  int b = blockIdx.x, t = threadIdx.x;
  int lane = t & 63, wave = t >> 6;
  if (t < 64) {
    int v = 0;
    for (int i = t; i < b; i += 64) v += sums[i];
    for (int o = 32; o; o >>= 1) v += __shfl_down(v, o);
    if (t == 0) off_s = v;
  }
  int i0 = b * SCAN_CHUNK + t * 4;
  int c0 = (i0 + 0 < n) ? cnt[i0 + 0] : 0;
  int c1 = (i0 + 1 < n) ? cnt[i0 + 1] : 0;
  int c2 = (i0 + 2 < n) ? cnt[i0 + 2] : 0;
  int c3 = (i0 + 3 < n) ? cnt[i0 + 3] : 0;
  int s = c0 + c1 + c2 + c3;
  int inc = s;
  for (int d = 1; d < 64; d <<= 1) {
    int v = __shfl_up(inc, d);
    if (lane >= d) inc += v;
  }
  if (lane == 63) wsum[wave] = inc;
  __syncthreads();
  int wbase = 0;
  if (wave > 0) wbase += wsum[0];
  if (wave > 1) wbase += wsum[1];
  if (wave > 2) wbase += wsum[2];
  int ex = off_s + wbase + inc - s;
  if (i0 + 0 < n) cnt[i0 + 0] = ex;
  if (i0 + 1 < n) cnt[i0 + 1] = ex + c0;
  if (i0 + 2 < n) cnt[i0 + 2] = ex + c0 + c1;
  if (i0 + 3 < n) cnt[i0 + 3] = ex + c0 + c1 + c2;
}

// scatter packed (src<<8)|etype  -- gather then reads ONE coalesced stream
__global__ __launch_bounds__(256) void k_scatter_packed(
    const int* __restrict__ src, const int* __restrict__ dst,
    const int* __restrict__ et, const int* __restrict__ dir,
    int* __restrict__ cursor, int* __restrict__ perm, int n_edges) {
  int i = blockIdx.x * blockDim.x + threadIdx.x;
  int stride = gridDim.x * blockDim.x;
  for (; i < n_edges; i += stride)
    if (dir[i] == 0) {
      int pos = atomicAdd(&cursor[dst[i]], 1);
      perm[pos] = (src[i] << 8) | et[i];
    }
}

// ---------------- gather: out[n] += sum_{e in bucket(n)} X[src[e]] - R[et[e]]
__global__ __launch_bounds__(256) void k_gather(
    const int* __restrict__ cursor, const int* __restrict__ perm,
    const float* __restrict__ X, const float* __restrict__ R,
    float* __restrict__ out, int n_nodes) {
  int lane = threadIdx.x & 63;
  int wave_id = (int)((blockIdx.x * blockDim.x + threadIdx.x) >> 6);
  int n_waves = (int)((gridDim.x * blockDim.x) >> 6);
  for (int node = wave_id; node < n_nodes; node += n_waves) {
    int end = cursor[node];
    int beg = (node == 0) ? 0 : cursor[node - 1];
    if (end <= beg) continue;
    float acc = 0.f;
    int k = beg;
    for (; k + 3 < end; k += 4) {  // 4-wide for MLP
      int p0 = perm[k], p1 = perm[k + 1], p2 = perm[k + 2], p3 = perm[k + 3];
      float a0 = X[(size_t)(p0 >> 8) * D + lane] - R[(size_t)(p0 & 255) * D + lane];
      float a1 = X[(size_t)(p1 >> 8) * D + lane] - R[(size_t)(p1 & 255) * D + lane];
      float a2 = X[(size_t)(p2 >> 8) * D + lane] - R[(size_t)(p2 & 255) * D + lane];
      float a3 = X[(size_t)(p3 >> 8) * D + lane] - R[(size_t)(p3 & 255) * D + lane];
      acc += (a0 + a1) + (a2 + a3);
    }
    for (; k < end; ++k) {
      int p = perm[k];
      acc += X[(size_t)(p >> 8) * D + lane] - R[(size_t)(p & 255) * D + lane];
    }
    out[(size_t)node * D + lane] += acc;
  }
}

// ---------------- fallback edge kernel (atomic) ----------------
__global__ __launch_bounds__(256) void edge_atomic(
    const int* __restrict__ src, const int* __restrict__ dst,
    const int* __restrict__ et, const int* __restrict__ dir,
    const float* __restrict__ X, const float* __restrict__ R,
    float* __restrict__ out, int n_edges) {
  int lane = threadIdx.x & 63;
  long long wave_id = ((long long)blockIdx.x * blockDim.x + threadIdx.x) >> 6;
  long long n_waves = ((long long)gridDim.x * blockDim.x) >> 6;
  for (long long base = wave_id * 64; base < n_edges; base += n_waves * 64) {
    int e = (int)base + lane;
    int s_l = 0, d_l = 0, t_l = 0, dir_l = 1;
    if (e < n_edges) {
      s_l = src[e]; d_l = dst[e]; t_l = et[e]; dir_l = dir[e];
    }
    int cnt = min(64, n_edges - (int)base);
    for (int i = 0; i < cnt; ++i) {
      int dir_i = __shfl(dir_l, i);
      if (dir_i != 0) continue;
      int s_i = __shfl(s_l, i);
      int t_i = __shfl(t_l, i);
      int d_i = __shfl(d_l, i);
      float val = X[(size_t)s_i * D + lane] - R[(size_t)t_i * D + lane];
      atomicAdd(&out[(size_t)d_i * D + lane], val);
    }
  }
}

extern "C" void kernel_launch(void* const* d_in, const int* in_sizes, int n_in,
                              void* d_out, int out_size, void* d_ws, size_t ws_size,
                              hipStream_t stream) {
  const float* node_feat = (const float*)d_in[0];
  const float* rel_emb   = (const float*)d_in[1];
  const int*   src       = (const int*)d_in[2];
  const int*   dst       = (const int*)d_in[3];
  const int*   etype     = (const int*)d_in[4];
  const int*   direction = (const int*)d_in[5];
  const float* W_self    = (const float*)d_in[6];
  const float* W_forward = (const float*)d_in[7];
  // d_in[8] = W_backward (unused: backward edges contribute zero)
  const float* W_rel     = (const float*)d_in[9];
  const float* bias      = (const float*)d_in[10];

  int n_nodes = in_sizes[0] / D;
  int n_rel   = in_sizes[1] / D;
  int n_edges = in_sizes[2];

  float* out     = (float*)d_out;
  float* rel_out = out + (size_t)n_nodes * D;

  // ws layout
  char* ws = (char*)d_ws;
  size_t offX = 0;
  size_t offR = offX + (size_t)n_nodes * D * 4;
  size_t offCur = offR + (size_t)n_rel * D * 4;
  size_t offSums = offCur + (size_t)n_nodes * 4;
  size_t offPerm = offSums + 1024 * 4;
  size_t need = offPerm + (size_t)n_edges * 4;

  float* X = (float*)(ws + offX);
  float* R = (float*)(ws + offR);
  int* cursor = (int*)(ws + offCur);
  int* sums = (int*)(ws + offSums);
  int* perm = (int*)(ws + offPerm);

  // 1) R and rel_out
  rel_kernel<<<50, 256, 0, stream>>>(rel_emb, W_forward, W_rel, R, rel_out, n_rel);

  // 2) out = nf@Ws^T + bias ; X = nf@Wf^T
  node_fused<<<1024, 256, 0, stream>>>(node_feat, W_self, W_forward, bias,
                                       out, X, n_nodes);

  bool packed_ok = (n_rel <= 256) && (n_nodes < (1 << 23));
  if (ws_size >= need && packed_ok) {
    int nblk = (n_nodes + SCAN_CHUNK - 1) / SCAN_CHUNK;
    hipMemsetAsync(cursor, 0, (size_t)(n_nodes + 1024) * 4, stream);
    k_hist<<<1024, 256, 0, stream>>>(dst, direction, cursor, n_edges);
    k_sums<<<nblk, 256, 0, stream>>>(cursor, sums, n_nodes);
    k_scan_chunks<<<nblk, 256, 0, stream>>>(cursor, sums, n_nodes);
    k_scatter_packed<<<1024, 256, 0, stream>>>(src, dst, etype, direction,
                                               cursor, perm, n_edges);
    k_gather<<<2048, 256, 0, stream>>>(cursor, perm, X, R, out, n_nodes);
  } else {
    edge_atomic<<<2048, 256, 0, stream>>>(src, dst, etype, direction, X, R, out,
                                          n_edges);
  }
}

// Round 9
// 136.994 us; speedup vs baseline: 6.1547x; 1.1082x over previous
//
#include <hip/hip_runtime.h>

#define D 64
#define SCAN_CHUNK 1024

typedef short bf16x8 __attribute__((ext_vector_type(8)));
typedef float f32x4 __attribute__((ext_vector_type(4)));

__device__ __forceinline__ short f2bf(float x) {
  unsigned u = __builtin_bit_cast(unsigned, x);
  u = u + 0x7FFFu + ((u >> 16) & 1u);   // round-to-nearest-even
  return (short)(u >> 16);
}

// ---------------- rel kernel: R = rel_emb @ Wf^T ; rel_out = rel_emb @ Wrel^T
// (f32 exact; tiny)
__global__ __launch_bounds__(256) void rel_kernel(
    const float* __restrict__ rel_emb,
    const float* __restrict__ W_f,
    const float* __restrict__ W_rel,
    float* __restrict__ R,
    float* __restrict__ rel_out,
    int n_rel) {
  __shared__ float WtF[D][D];
  __shared__ float WtR[D][D];
  int tid = threadIdx.x;
  for (int idx = tid; idx < D * D; idx += 256) {
    int j = idx >> 6, k = idx & 63;
    WtF[k][j] = W_f[idx];
    WtR[k][j] = W_rel[idx];
  }
  __syncthreads();
  int lane = tid & 63, wave = tid >> 6;
  for (int r = blockIdx.x * 4 + wave; r < n_rel; r += gridDim.x * 4) {
    const float4* a = (const float4*)(rel_emb + (size_t)r * D);
    float accR = 0.f, accO = 0.f;
#pragma unroll
    for (int k4 = 0; k4 < 16; ++k4) {
      float4 av = a[k4];
      int k = k4 * 4;
      accR += av.x * WtF[k][lane] + av.y * WtF[k + 1][lane] +
              av.z * WtF[k + 2][lane] + av.w * WtF[k + 3][lane];
      accO += av.x * WtR[k][lane] + av.y * WtR[k + 1][lane] +
              av.z * WtR[k + 2][lane] + av.w * WtR[k + 3][lane];
    }
    R[(size_t)r * D + lane] = accR;
    rel_out[(size_t)r * D + lane] = accO;
  }
}

// ---------------- node GEMM via MFMA (bf16 inputs, f32 accum):
// out[16t..][64] = nf @ Ws^T + bias ; X = nf @ Wf^T
// mfma_f32_16x16x32_bf16. Layouts (guide m89-verified D): A: row=lane&15,
// k=(lane>>4)*8+i ; B: col=lane&15, k=(lane>>4)*8+i (B[k][n]=W[n][k]);
// D: col=lane&15, row=(lane>>4)*4+reg.
__global__ __launch_bounds__(256) void node_mfma(
    const float* __restrict__ nf,
    const float* __restrict__ W_self,
    const float* __restrict__ W_f,
    const float* __restrict__ bias,
    float* __restrict__ out,
    float* __restrict__ X,
    int n_nodes) {
  int tid = threadIdx.x;
  int lane = tid & 63;
  int l15 = lane & 15;
  int kg = lane >> 4;

  // B-fragments for both matrices, 4 column-tiles x 2 K-halves
  bf16x8 bS[4][2], bF[4][2];
#pragma unroll
  for (int q = 0; q < 4; ++q) {
#pragma unroll
    for (int h = 0; h < 2; ++h) {
      const float* ps = W_self + (size_t)(q * 16 + l15) * D + h * 32 + kg * 8;
      const float* pf = W_f + (size_t)(q * 16 + l15) * D + h * 32 + kg * 8;
      float4 s0 = *(const float4*)ps, s1 = *(const float4*)(ps + 4);
      float4 f0 = *(const float4*)pf, f1 = *(const float4*)(pf + 4);
      bf16x8 vs, vf;
      vs[0] = f2bf(s0.x); vs[1] = f2bf(s0.y); vs[2] = f2bf(s0.z); vs[3] = f2bf(s0.w);
      vs[4] = f2bf(s1.x); vs[5] = f2bf(s1.y); vs[6] = f2bf(s1.z); vs[7] = f2bf(s1.w);
      vf[0] = f2bf(f0.x); vf[1] = f2bf(f0.y); vf[2] = f2bf(f0.z); vf[3] = f2bf(f0.w);
      vf[4] = f2bf(f1.x); vf[5] = f2bf(f1.y); vf[6] = f2bf(f1.z); vf[7] = f2bf(f1.w);
      bS[q][h] = vs;
      bF[q][h] = vf;
    }
  }
  float bq[4];
#pragma unroll
  for (int q = 0; q < 4; ++q) bq[q] = bias[q * 16 + l15];

  int wave = (int)((blockIdx.x * blockDim.x + tid) >> 6);
  int n_waves = (int)((gridDim.x * blockDim.x) >> 6);
  int ntiles = (n_nodes + 15) >> 4;

  for (int t = wave; t < ntiles; t += n_waves) {
    int base = t << 4;
    int arow = base + l15;
    if (arow >= n_nodes) arow = n_nodes - 1;
    const float* ap = nf + (size_t)arow * D + kg * 8;
    float4 a00 = *(const float4*)ap;
    float4 a01 = *(const float4*)(ap + 4);
    float4 a10 = *(const float4*)(ap + 32);
    float4 a11 = *(const float4*)(ap + 36);
    bf16x8 af0, af1;
    af0[0] = f2bf(a00.x); af0[1] = f2bf(a00.y); af0[2] = f2bf(a00.z); af0[3] = f2bf(a00.w);
    af0[4] = f2bf(a01.x); af0[5] = f2bf(a01.y); af0[6] = f2bf(a01.z); af0[7] = f2bf(a01.w);
    af1[0] = f2bf(a10.x); af1[1] = f2bf(a10.y); af1[2] = f2bf(a10.z); af1[3] = f2bf(a10.w);
    af1[4] = f2bf(a11.x); af1[5] = f2bf(a11.y); af1[6] = f2bf(a11.z); af1[7] = f2bf(a11.w);

    bool full = (base + 16 <= n_nodes);
#pragma unroll
    for (int q = 0; q < 4; ++q) {
      f32x4 accS = {0.f, 0.f, 0.f, 0.f};
      f32x4 accF = {0.f, 0.f, 0.f, 0.f};
      accS = __builtin_amdgcn_mfma_f32_16x16x32_bf16(af0, bS[q][0], accS, 0, 0, 0);
      accS = __builtin_amdgcn_mfma_f32_16x16x32_bf16(af1, bS[q][1], accS, 0, 0, 0);
      accF = __builtin_amdgcn_mfma_f32_16x16x32_bf16(af0, bF[q][0], accF, 0, 0, 0);
      accF = __builtin_amdgcn_mfma_f32_16x16x32_bf16(af1, bF[q][1], accF, 0, 0, 0);
      int col = q * 16 + l15;
      int row0 = base + kg * 4;                 // D row base for this lane
      size_t o = (size_t)row0 * D + col;
      if (full) {
#pragma unroll
        for (int r = 0; r < 4; ++r) {
          out[o + (size_t)r * D] = accS[r] + bq[q];
          X[o + (size_t)r * D] = accF[r];
        }
      } else {
#pragma unroll
        for (int r = 0; r < 4; ++r) {
          if (row0 + r < n_nodes) {
            out[o + (size_t)r * D] = accS[r] + bq[q];
            X[o + (size_t)r * D] = accF[r];
          }
        }
      }
    }
  }
}

// ---------------- CSR build ----------------
__global__ __launch_bounds__(256) void k_hist(
    const int* __restrict__ dst, const int* __restrict__ dir,
    int* __restrict__ cnt, int n_edges) {
  int i = blockIdx.x * blockDim.x + threadIdx.x;
  int stride = gridDim.x * blockDim.x;
  for (; i < n_edges; i += stride)
    if (dir[i] == 0) atomicAdd(&cnt[dst[i]], 1);
}

__global__ __launch_bounds__(256) void k_sums(
    const int* __restrict__ cnt, int* __restrict__ sums, int n) {
  __shared__ int ws_[4];
  int b = blockIdx.x, t = threadIdx.x;
  int lane = t & 63, wave = t >> 6;
  int s = 0;
  for (int j = 0; j < 4; ++j) {
    int i = b * SCAN_CHUNK + t * 4 + j;
    if (i < n) s += cnt[i];
  }
  for (int off = 32; off; off >>= 1) s += __shfl_down(s, off);
  if (lane == 0) ws_[wave] = s;
  __syncthreads();
  if (t == 0) sums[b] = ws_[0] + ws_[1] + ws_[2] + ws_[3];
}

// local scan of chunk + on-the-fly block offset
__global__ __launch_bounds__(256) void k_scan_chunks(
    int* __restrict__ cnt, const int* __restrict__ sums, int n) {
  __shared__ int wsum[4];
  __shared__ int off_s;
  int b = blockIdx.x, t = threadIdx.x;
  int lane = t & 63, wave = t >> 6;
  if (t < 64) {
    int v = 0;
    for (int i = t; i < b; i += 64) v += sums[i];
    for (int o = 32; o; o >>= 1) v += __shfl_down(v, o);
    if (t == 0) off_s = v;
  }
  int i0 = b * SCAN_CHUNK + t * 4;
  int c0 = (i0 + 0 < n) ? cnt[i0 + 0] : 0;
  int c1 = (i0 + 1 < n) ? cnt[i0 + 1] : 0;
  int c2 = (i0 + 2 < n) ? cnt[i0 + 2] : 0;
  int c3 = (i0 + 3 < n) ? cnt[i0 + 3] : 0;
  int s = c0 + c1 + c2 + c3;
  int inc = s;
  for (int d = 1; d < 64; d <<= 1) {
    int v = __shfl_up(inc, d);
    if (lane >= d) inc += v;
  }
  if (lane == 63) wsum[wave] = inc;
  __syncthreads();
  int wbase = 0;
  if (wave > 0) wbase += wsum[0];
  if (wave > 1) wbase += wsum[1];
  if (wave > 2) wbase += wsum[2];
  int ex = off_s + wbase + inc - s;
  if (i0 + 0 < n) cnt[i0 + 0] = ex;
  if (i0 + 1 < n) cnt[i0 + 1] = ex + c0;
  if (i0 + 2 < n) cnt[i0 + 2] = ex + c0 + c1;
  if (i0 + 3 < n) cnt[i0 + 3] = ex + c0 + c1 + c2;
}

// scatter packed (src<<8)|etype
__global__ __launch_bounds__(256) void k_scatter_packed(
    const int* __restrict__ src, const int* __restrict__ dst,
    const int* __restrict__ et, const int* __restrict__ dir,
    int* __restrict__ cursor, int* __restrict__ perm, int n_edges) {
  int i = blockIdx.x * blockDim.x + threadIdx.x;
  int stride = gridDim.x * blockDim.x;
  for (; i < n_edges; i += stride)
    if (dir[i] == 0) {
      int pos = atomicAdd(&cursor[dst[i]], 1);
      perm[pos] = (src[i] << 8) | et[i];
    }
}

// ---------------- gather: out[n] += sum_{e in bucket(n)} X[src[e]] - R[et[e]]
__global__ __launch_bounds__(256) void k_gather(
    const int* __restrict__ cursor, const int* __restrict__ perm,
    const float* __restrict__ X, const float* __restrict__ R,
    float* __restrict__ out, int n_nodes) {
  int lane = threadIdx.x & 63;
  int wave_id = (int)((blockIdx.x * blockDim.x + threadIdx.x) >> 6);
  int n_waves = (int)((gridDim.x * blockDim.x) >> 6);
  for (int node = wave_id; node < n_nodes; node += n_waves) {
    int end = cursor[node];
    int beg = (node == 0) ? 0 : cursor[node - 1];
    if (end <= beg) continue;
    float acc = 0.f;
    int k = beg;
    for (; k + 3 < end; k += 4) {
      int p0 = perm[k], p1 = perm[k + 1], p2 = perm[k + 2], p3 = perm[k + 3];
      float a0 = X[(size_t)(p0 >> 8) * D + lane] - R[(size_t)(p0 & 255) * D + lane];
      float a1 = X[(size_t)(p1 >> 8) * D + lane] - R[(size_t)(p1 & 255) * D + lane];
      float a2 = X[(size_t)(p2 >> 8) * D + lane] - R[(size_t)(p2 & 255) * D + lane];
      float a3 = X[(size_t)(p3 >> 8) * D + lane] - R[(size_t)(p3 & 255) * D + lane];
      acc += (a0 + a1) + (a2 + a3);
    }
    for (; k < end; ++k) {
      int p = perm[k];
      acc += X[(size_t)(p >> 8) * D + lane] - R[(size_t)(p & 255) * D + lane];
    }
    out[(size_t)node * D + lane] += acc;
  }
}

// ---------------- fallback edge kernel (atomic) ----------------
__global__ __launch_bounds__(256) void edge_atomic(
    const int* __restrict__ src, const int* __restrict__ dst,
    const int* __restrict__ et, const int* __restrict__ dir,
    const float* __restrict__ X, const float* __restrict__ R,
    float* __restrict__ out, int n_edges) {
  int lane = threadIdx.x & 63;
  long long wave_id = ((long long)blockIdx.x * blockDim.x + threadIdx.x) >> 6;
  long long n_waves = ((long long)gridDim.x * blockDim.x) >> 6;
  for (long long base = wave_id * 64; base < n_edges; base += n_waves * 64) {
    int e = (int)base + lane;
    int s_l = 0, d_l = 0, t_l = 0, dir_l = 1;
    if (e < n_edges) {
      s_l = src[e]; d_l = dst[e]; t_l = et[e]; dir_l = dir[e];
    }
    int cnt = min(64, n_edges - (int)base);
    for (int i = 0; i < cnt; ++i) {
      int dir_i = __shfl(dir_l, i);
      if (dir_i != 0) continue;
      int s_i = __shfl(s_l, i);
      int t_i = __shfl(t_l, i);
      int d_i = __shfl(d_l, i);
      float val = X[(size_t)s_i * D + lane] - R[(size_t)t_i * D + lane];
      atomicAdd(&out[(size_t)d_i * D + lane], val);
    }
  }
}

extern "C" void kernel_launch(void* const* d_in, const int* in_sizes, int n_in,
                              void* d_out, int out_size, void* d_ws, size_t ws_size,
                              hipStream_t stream) {
  const float* node_feat = (const float*)d_in[0];
  const float* rel_emb   = (const float*)d_in[1];
  const int*   src       = (const int*)d_in[2];
  const int*   dst       = (const int*)d_in[3];
  const int*   etype     = (const int*)d_in[4];
  const int*   direction = (const int*)d_in[5];
  const float* W_self    = (const float*)d_in[6];
  const float* W_forward = (const float*)d_in[7];
  // d_in[8] = W_backward (unused: backward edges contribute zero)
  const float* W_rel     = (const float*)d_in[9];
  const float* bias      = (const float*)d_in[10];

  int n_nodes = in_sizes[0] / D;
  int n_rel   = in_sizes[1] / D;
  int n_edges = in_sizes[2];

  float* out     = (float*)d_out;
  float* rel_out = out + (size_t)n_nodes * D;

  // ws layout
  char* ws = (char*)d_ws;
  size_t offX = 0;
  size_t offR = offX + (size_t)n_nodes * D * 4;
  size_t offCur = offR + (size_t)n_rel * D * 4;
  size_t offSums = offCur + (size_t)n_nodes * 4;
  size_t offPerm = offSums + 1024 * 4;
  size_t need = offPerm + (size_t)n_edges * 4;

  float* X = (float*)(ws + offX);
  float* R = (float*)(ws + offR);
  int* cursor = (int*)(ws + offCur);
  int* sums = (int*)(ws + offSums);
  int* perm = (int*)(ws + offPerm);

  // 1) R and rel_out
  rel_kernel<<<50, 256, 0, stream>>>(rel_emb, W_forward, W_rel, R, rel_out, n_rel);

  // 2) out = nf@Ws^T + bias ; X = nf@Wf^T  via bf16 MFMA
  int ntiles = (n_nodes + 15) / 16;
  int nblocks = (ntiles + 3) / 4;  // 4 waves/block, 1 tile/wave
  node_mfma<<<nblocks, 256, 0, stream>>>(node_feat, W_self, W_forward, bias,
                                         out, X, n_nodes);

  bool packed_ok = (n_rel <= 256) && (n_nodes < (1 << 23));
  if (ws_size >= need && packed_ok) {
    int nblk = (n_nodes + SCAN_CHUNK - 1) / SCAN_CHUNK;
    hipMemsetAsync(cursor, 0, (size_t)(n_nodes + 1024) * 4, stream);
    k_hist<<<1024, 256, 0, stream>>>(dst, direction, cursor, n_edges);
    k_sums<<<nblk, 256, 0, stream>>>(cursor, sums, n_nodes);
    k_scan_chunks<<<nblk, 256, 0, stream>>>(cursor, sums, n_nodes);
    k_scatter_packed<<<1024, 256, 0, stream>>>(src, dst, etype, direction,
                                               cursor, perm, n_edges);
    k_gather<<<2048, 256, 0, stream>>>(cursor, perm, X, R, out, n_nodes);
  } else {
    edge_atomic<<<2048, 256, 0, stream>>>(src, dst, etype, direction, X, R, out,
                                          n_edges);
  }
}